// Round 1
// baseline (192.037 us; speedup 1.0000x reference)
//
#include <hip/hip_runtime.h>

// Problem constants (GatedEncoderLayer): B=16, I=2048, J=1024, K=1024, F=32
constexpr int kI = 2048;
constexpr int kJ = 1024;
constexpr int kK = 1024;
constexpr int kF = 32;
constexpr int kRows = 16 * 2048;   // B * I = 32768
constexpr int kRowsPerBlk = 64;
constexpr int kThreads = 256;

// out[row, k] = sum_f [ (sum_j x[row, j] * Wy[j, f]) * Wx[row % I, f] ] * Wz[k, f]
__global__ __launch_bounds__(kThreads, 2)
void gated_encoder_fused(const float* __restrict__ x,
                         const float* __restrict__ Wx,
                         const float* __restrict__ Wy,
                         const float* __restrict__ Wz,
                         float* __restrict__ out)
{
    // t2 tile: 64 rows x 32 f, padded to 36 floats/row (16B-aligned stride,
    // spreads the stage-1 write banks; stage-2 reads are uniform-address
    // broadcasts so they never conflict).
    __shared__ float t2[kRowsPerBlk][kF + 4];

    const int tid  = threadIdx.x;
    const int lane = tid & 63;
    const int wv   = tid >> 6;

    // ---------------- stage 1 ----------------
    // thread -> (row, f-octet): 4 lanes per row, each owns 8 consecutive f.
    const int rloc = wv * 16 + (lane >> 2);            // 0..63 within block
    const int row  = blockIdx.x * kRowsPerBlk + rloc;  // global row (b*I + i)
    const int fg8  = (lane & 3) * 8;                   // f base: 0/8/16/24

    const float* __restrict__ xrow = x + (size_t)row * kJ;

    float acc[8];
#pragma unroll
    for (int u = 0; u < 8; ++u) acc[u] = 0.0f;

    for (int j = 0; j < kJ; j += 8) {
        const float4 xv0 = *reinterpret_cast<const float4*>(xrow + j);
        const float4 xv1 = *reinterpret_cast<const float4*>(xrow + j + 4);
        const float xs[8] = {xv0.x, xv0.y, xv0.z, xv0.w,
                             xv1.x, xv1.y, xv1.z, xv1.w};
#pragma unroll
        for (int u = 0; u < 8; ++u) {
            const float* wyp = Wy + (size_t)(j + u) * kF + fg8;
            const float4 w0 = *reinterpret_cast<const float4*>(wyp);
            const float4 w1 = *reinterpret_cast<const float4*>(wyp + 4);
            acc[0] = fmaf(xs[u], w0.x, acc[0]);
            acc[1] = fmaf(xs[u], w0.y, acc[1]);
            acc[2] = fmaf(xs[u], w0.z, acc[2]);
            acc[3] = fmaf(xs[u], w0.w, acc[3]);
            acc[4] = fmaf(xs[u], w1.x, acc[4]);
            acc[5] = fmaf(xs[u], w1.y, acc[5]);
            acc[6] = fmaf(xs[u], w1.z, acc[6]);
            acc[7] = fmaf(xs[u], w1.w, acc[7]);
        }
    }

    // gate by Wx[i, f] and stash into LDS
    const int i = row & (kI - 1);
    const float* wxp = Wx + (size_t)i * kF + fg8;
    const float4 g0 = *reinterpret_cast<const float4*>(wxp);
    const float4 g1 = *reinterpret_cast<const float4*>(wxp + 4);
    float4 r0, r1;
    r0.x = acc[0] * g0.x;  r0.y = acc[1] * g0.y;
    r0.z = acc[2] * g0.z;  r0.w = acc[3] * g0.w;
    r1.x = acc[4] * g1.x;  r1.y = acc[5] * g1.y;
    r1.z = acc[6] * g1.z;  r1.w = acc[7] * g1.w;
    *reinterpret_cast<float4*>(&t2[rloc][fg8])     = r0;
    *reinterpret_cast<float4*>(&t2[rloc][fg8 + 4]) = r1;

    __syncthreads();

    // ---------------- stage 2 ----------------
    // thread owns 2 k-columns per pass, 2 passes -> 1024 k total.
    const size_t outBase = (size_t)blockIdx.x * kRowsPerBlk * kK;

#pragma unroll
    for (int pass = 0; pass < 2; ++pass) {
        const int k1 = pass * 512 + tid;   // lanes consecutive -> coalesced stores
        const int k2 = k1 + 256;
        const float* wz1 = Wz + (size_t)k1 * kF;
        const float* wz2 = Wz + (size_t)k2 * kF;
        float4 z1[8], z2[8];
#pragma unroll
        for (int m = 0; m < 8; ++m) {
            z1[m] = *reinterpret_cast<const float4*>(wz1 + 4 * m);
            z2[m] = *reinterpret_cast<const float4*>(wz2 + 4 * m);
        }
        for (int r = 0; r < kRowsPerBlk; ++r) {
            float4 a1 = {0.f, 0.f, 0.f, 0.f};
            float4 a2 = {0.f, 0.f, 0.f, 0.f};
#pragma unroll
            for (int m = 0; m < 8; ++m) {
                const float4 tv = *reinterpret_cast<const float4*>(&t2[r][4 * m]);
                a1.x = fmaf(tv.x, z1[m].x, a1.x);
                a1.y = fmaf(tv.y, z1[m].y, a1.y);
                a1.z = fmaf(tv.z, z1[m].z, a1.z);
                a1.w = fmaf(tv.w, z1[m].w, a1.w);
                a2.x = fmaf(tv.x, z2[m].x, a2.x);
                a2.y = fmaf(tv.y, z2[m].y, a2.y);
                a2.z = fmaf(tv.z, z2[m].z, a2.z);
                a2.w = fmaf(tv.w, z2[m].w, a2.w);
            }
            const float s1 = (a1.x + a1.y) + (a1.z + a1.w);
            const float s2 = (a2.x + a2.y) + (a2.z + a2.w);
            out[outBase + (size_t)r * kK + k1] = s1;
            out[outBase + (size_t)r * kK + k2] = s2;
        }
    }
}

extern "C" void kernel_launch(void* const* d_in, const int* in_sizes, int n_in,
                              void* d_out, int out_size, void* d_ws, size_t ws_size,
                              hipStream_t stream) {
    const float* x  = (const float*)d_in[0];   // matrix_batch (B, I, J)
    const float* Wx = (const float*)d_in[1];   // (I, F)
    const float* Wy = (const float*)d_in[2];   // (J, F)
    const float* Wz = (const float*)d_in[3];   // (K, F)
    float* out = (float*)d_out;                // (B, I, K) float32

    dim3 grid(kRows / kRowsPerBlk);            // 512 blocks
    gated_encoder_fused<<<grid, kThreads, 0, stream>>>(x, Wx, Wy, Wz, out);
}